// Round 9
// baseline (262.730 us; speedup 1.0000x reference)
//
#include <hip/hip_runtime.h>

#define NROWS   262144
#define NCODES  1024
#define DIM     64
#define NTILES  64       // 16-code MFMA tiles covering 1024 codes
#define TILEB   2048     // bytes per tile in fragment layout (2 x 1024)
#define PADT    4        // prefetch overrun pad (tiles 64..67 read, never used)

typedef _Float16 half8 __attribute__((ext_vector_type(8)));
typedef __attribute__((ext_vector_type(4))) float f32x4;

#define MFMA16(acc, a, b) acc = __builtin_amdgcn_mfma_f32_16x16x32_f16(a, b, acc, 0, 0, 0)

// ---------------------------------------------------------------------------
// Prep: arithmetic bit-identical to the validated version. fp16 codebook in
// MFMA B-fragment order (R3-validated layout, TILEB=2048). E^2 plain-stored
// per prep-wave into eslots[16] (no atomicMax -> no memset dispatch).
// ---------------------------------------------------------------------------
__global__ __launch_bounds__(256) void vq_prep(const float* __restrict__ cb,
                                               float* __restrict__ hcsq,
                                               char* __restrict__ stream,
                                               float* __restrict__ eslots) {
    const int k = blockIdx.x * 256 + threadIdx.x;   // 0..1023
    const float4* row = (const float4*)(cb + (size_t)k * DIM);
    char* base = stream + (size_t)(k >> 4) * TILEB + (size_t)(k & 15) * 16;
    float s = 0.f, r2 = 0.f;
#pragma unroll
    for (int i = 0; i < 8; ++i) {   // chunk i: halves i*8..i*8+7
        float4 a = row[2 * i], b = row[2 * i + 1];
        float v[8] = {a.x, a.y, a.z, a.w, b.x, b.y, b.z, b.w};
        union { half8 f; _Float16 e[8]; } uh;
#pragma unroll
        for (int j = 0; j < 8; ++j) {
            float c = v[j];
            s += c * c;                    // sequential chain (matches r4/r1)
            _Float16 h = (_Float16)c;      // RNE
            uh.e[j] = h;
            float d = c - (float)h;        // true residual
            r2 += d * d;
        }
        // chunk i -> j = i>>2 slot, q-position = i&3 (validated R3 layout)
        *(half8*)(base + ((i >> 2) << 10) + ((i & 3) << 8)) = uh.f;
    }
    hcsq[k] = 0.5f * s;
    float w = r2;
#pragma unroll
    for (int off = 1; off < 64; off <<= 1) w = fmaxf(w, __shfl_xor(w, off));
    if ((threadIdx.x & 63) == 0)
        eslots[blockIdx.x * 4 + (threadIdx.x >> 6)] = w;   // plain store
}

// ---------------------------------------------------------------------------
// Main. R3's 97-us loop body VERBATIM (acc init = -hc from LDS inside the
// phase, 4-tile rotating register prefetch, lag-1 select) -- R8's SELECT-side
// subtract reverted (+6 us of issue). Epilogue: flags pooled in a per-block
// LDS list; after one barrier the block's 4 waves rescue pooled rows
// round-robin. Rationale (R7 post-mortem): the whole 2048-block grid is
// co-resident, so the rescue phase starts grid-wide nearly simultaneously ->
// every SIMD has ~8 active rescue waves -> TLP hides the L2 load latency
// exactly as in the standalone rescue kernel; pooling caps the worst wave at
// ~4 rows. R7's 148-us tail was lone straggler waves with ZERO TLP (9 rows x
// 21 us exposed-latency each), not register starvation.
// ---------------------------------------------------------------------------
#define SELECT(aa, ab, tl)                                                        \
    {                                                                             \
        const int _tl = (tl);                                                     \
        _Pragma("unroll")                                                         \
        for (int r = 0; r < 4; ++r) {                                             \
            float s0 = (aa)[r];                                                   \
            bool g0 = s0 > best[0][r];                                            \
            second[0][r] = __builtin_amdgcn_fmed3f(s0, best[0][r], second[0][r]); \
            best[0][r] = g0 ? s0 : best[0][r];                                    \
            btile[0][r] = g0 ? _tl : btile[0][r];                                 \
            float s1 = (ab)[r];                                                   \
            bool g1 = s1 > best[1][r];                                            \
            second[1][r] = __builtin_amdgcn_fmed3f(s1, best[1][r], second[1][r]); \
            best[1][r] = g1 ? s1 : best[1][r];                                    \
            btile[1][r] = g1 ? _tl : btile[1][r];                                 \
        }                                                                         \
    }

// One tile: select the OTHER acc pair (lag-1), init this pair to -hc (LDS
// read, covered by the SELECT), 8 MFMA from fragment regs, refill frags with
// the tile 4 ahead. (R3-verbatim)
#define PHASE(fA, fB, a0, a1, o0, o1, TT)                     \
    {                                                         \
        const int _T = (TT);                                  \
        float nh = nshc[_T * 16 + m];                         \
        SELECT(o0, o1, _T - 1);                               \
        a0 = (f32x4){nh, nh, nh, nh};                         \
        a1 = a0;                                              \
        MFMA16(a0, xh[0][0], fA); MFMA16(a1, xh[1][0], fA);   \
        MFMA16(a0, xh[0][1], fB); MFMA16(a1, xh[1][1], fB);   \
        MFMA16(a0, xl[0][0], fA); MFMA16(a1, xl[1][0], fA);   \
        MFMA16(a0, xl[0][1], fB); MFMA16(a1, xl[1][1], fB);   \
        fA = *(const half8*)(gpre);                           \
        fB = *(const half8*)(gpre + 1024);                    \
        gpre += TILEB;                                        \
    }

__global__ __launch_bounds__(256, 4) void vq_main(const float* __restrict__ inputs,
                                                  const float* __restrict__ cb,
                                                  const float* __restrict__ hcsq,
                                                  const char* __restrict__ stream,
                                                  const float* __restrict__ eslots,
                                                  float* __restrict__ out) {
    __shared__ float nshc[NCODES];     // negated 0.5||c||^2 (4 KB, loaded once)
    __shared__ unsigned s_rows[128];   // block-pooled flagged rows (cap = rows/block)
    __shared__ unsigned s_cnt;
    const int tid = threadIdx.x;
    const int lane = tid & 63;
    const int wave = tid >> 6;
    const int m = lane & 15;   // A row-in-tile / B code-in-tile / D col
    const int q = lane >> 4;   // k-quad
    const size_t rowbase = (size_t)blockIdx.x * 128 + (size_t)wave * 32;

    for (int i = tid; i < NCODES; i += 256) nshc[i] = -hcsq[i];
    if (tid == 0) s_cnt = 0u;

    float e2 = 0.f;
#pragma unroll
    for (int i = 0; i < 16; ++i) e2 = fmaxf(e2, eslots[i]);
    const float E = sqrtf(e2) * 1.001f;

    // A fragments (fp16 hi+lo of x) + exact row sum-of-squares for the margin.
    half8 xh[2][2], xl[2][2];
    float xsq[2];
#pragma unroll
    for (int t = 0; t < 2; ++t) {
        const float* px = inputs + (rowbase + t * 16 + m) * DIM;
        float acc = 0.f;
#pragma unroll
        for (int s = 0; s < 2; ++s) {
            const float4* p = (const float4*)(px + q * 8 + s * 32);
            float4 v0 = p[0], v1 = p[1];
            float v[8] = {v0.x, v0.y, v0.z, v0.w, v1.x, v1.y, v1.z, v1.w};
            union { half8 f; _Float16 e[8]; } uh, ul;
#pragma unroll
            for (int j = 0; j < 8; ++j) {
                acc += v[j] * v[j];
                _Float16 h = (_Float16)v[j];
                uh.e[j] = h;
                ul.e[j] = (_Float16)(v[j] - (float)h);
            }
            xh[t][s] = uh.f;
            xl[t][s] = ul.f;
        }
        acc += __shfl_xor(acc, 16);   // reduce across k-quads (same m)
        acc += __shfl_xor(acc, 32);
        xsq[t] = acc;
    }
    __syncthreads();   // nshc + s_cnt ready

    float best[2][4], second[2][4];
    int btile[2][4];
#pragma unroll
    for (int t = 0; t < 2; ++t)
#pragma unroll
        for (int r = 0; r < 4; ++r) {
            best[t][r] = -INFINITY;
            second[t][r] = -INFINITY;
            btile[t][r] = 0;
        }

    // 4-tile rotating register prefetch pipeline over the fragment-ordered
    // codebook (R3-verbatim).
    const char* gL = stream + (size_t)lane * 16;
    half8 f0a = *(const half8*)(gL);
    half8 f0b = *(const half8*)(gL + 1024);
    half8 f1a = *(const half8*)(gL + TILEB);
    half8 f1b = *(const half8*)(gL + TILEB + 1024);
    half8 f2a = *(const half8*)(gL + 2 * TILEB);
    half8 f2b = *(const half8*)(gL + 2 * TILEB + 1024);
    half8 f3a = *(const half8*)(gL + 3 * TILEB);
    half8 f3b = *(const half8*)(gL + 3 * TILEB + 1024);
    const char* gpre = gL + 4 * TILEB;

    // Lag-1 select pipeline; dummy -INF makes the first select a no-op.
    f32x4 accA0, accA1, accB0, accB1;
    accB0 = (f32x4){-INFINITY, -INFINITY, -INFINITY, -INFINITY};
    accB1 = accB0;

    for (int it = 0; it < 16; ++it) {
        const int T = it * 4;
        PHASE(f0a, f0b, accA0, accA1, accB0, accB1, T + 0);
        PHASE(f1a, f1b, accB0, accB1, accA0, accA1, T + 1);
        PHASE(f2a, f2b, accA0, accA1, accB0, accB1, T + 2);
        PHASE(f3a, f3b, accB0, accB1, accA0, accA1, T + 3);
    }
    SELECT(accB0, accB1, NTILES - 1);   // drain last pending tile

    // Cross-lane top-2 merge (16-lane groups), min-index tie-break; write
    // non-flagged rows; pool flagged rows into the block's LDS list.
#pragma unroll
    for (int t = 0; t < 2; ++t)
#pragma unroll
        for (int r = 0; r < 4; ++r) {
            float b = best[t][r], sc = second[t][r];
            int bi = btile[t][r] * 16 + m;   // reconstruct code index
#pragma unroll
            for (int off = 1; off < 16; off <<= 1) {
                float ob = __shfl_xor(b, off);
                float os = __shfl_xor(sc, off);
                int oi = __shfl_xor(bi, off);
                sc = fmaxf(fmaxf(sc, os), fminf(b, ob));
                if (ob > b || (ob == b && oi < bi)) { b = ob; bi = oi; }
            }
            size_t row = rowbase + t * 16 + q * 4 + r;
            float xs = __shfl(xsq[t], (lane & 48) | (q * 4 + r));
            float marg = 2.0f * (sqrtf(xs) * E + 1e-3f);
            bool flg = (b - sc) < marg;   // group-uniform (b, sc, xs uniform)
            if (!flg) {
                const float4* src = (const float4*)(cb + (size_t)bi * DIM);
                ((float4*)(out + row * DIM))[m] = src[m];
            } else if (m == 0) {
                unsigned p = atomicAdd(&s_cnt, 1u);   // LDS atomic
                s_rows[p] = (unsigned)row;            // p < 128 by construction
            }
        }

    __syncthreads();   // pool complete
    const unsigned n = s_cnt;

    // Block-pooled exact rescue: wave w takes pooled entries w, w+4, ...
    // Inner loop is the validated standalone rescue arithmetic VERBATIM.
    for (unsigned e = wave; e < n; e += 4) {
        const size_t row = s_rows[e];
        const int sub = lane & 15;  // dim quad
        const int g = lane >> 4;    // code within 4-group
        float4 xv = ((const float4*)(inputs + row * DIM))[sub];
        float rb = -INFINITY;
        int rbi = 0;
#pragma unroll 8
        for (int c4 = 0; c4 < NCODES / 4; ++c4) {
            int c = c4 * 4 + g;
            float4 cv = ((const float4*)(cb + (size_t)c * DIM))[sub];
            float p = xv.x * cv.x + xv.y * cv.y + xv.z * cv.z + xv.w * cv.w;
            p += __shfl_xor(p, 1);
            p += __shfl_xor(p, 2);
            p += __shfl_xor(p, 4);
            p += __shfl_xor(p, 8);
            float s = p - hcsq[c];
            if (s > rb) { rb = s; rbi = c; }
        }
#pragma unroll
        for (int off = 16; off < 64; off <<= 1) {
            float ob = __shfl_xor(rb, off);
            int oi = __shfl_xor(rbi, off);
            if (ob > rb || (ob == rb && oi < rbi)) { rb = ob; rbi = oi; }
        }
        out[row * DIM + lane] = cb[(size_t)rbi * DIM + lane];
    }
}

extern "C" void kernel_launch(void* const* d_in, const int* in_sizes, int n_in,
                              void* d_out, int out_size, void* d_ws, size_t ws_size,
                              hipStream_t stream_) {
    const float* inputs = (const float*)d_in[0];    // [262144, 64] fp32
    const float* cb = (const float*)d_in[1];        // [1024, 64] fp32
    float* out = (float*)d_out;

    // ws: hcsq f32[1024] | tile stream [68 x 2048 B] | eslots f32[16]
    char* ws = (char*)d_ws;
    float* hcsq = (float*)ws;                                       //   4 KiB
    char* strm = ws + 4096;                                         // 136 KiB
    float* eslots = (float*)(ws + 4096 + (NTILES + PADT) * TILEB);

    vq_prep<<<4, 256, 0, stream_>>>(cb, hcsq, strm, eslots);
    vq_main<<<NROWS / 128, 256, 0, stream_>>>(inputs, cb, hcsq, strm, eslots, out);
}

// Round 10
// 260.379 us; speedup vs baseline: 1.0090x; 1.0090x over previous
//
#include <hip/hip_runtime.h>

#define NROWS   262144
#define NCODES  1024
#define DIM     64
#define NTILES  64       // 16-code MFMA tiles covering 1024 codes
#define TILEB   2048     // bytes per tile in fragment layout (2 x 1024)
#define PADT    4        // prefetch overrun pad (tiles 64..67 read, never used)

typedef _Float16 half8 __attribute__((ext_vector_type(8)));
typedef __attribute__((ext_vector_type(4))) float f32x4;

#define MFMA16(acc, a, b) acc = __builtin_amdgcn_mfma_f32_16x16x32_f16(a, b, acc, 0, 0, 0)

// ---------------------------------------------------------------------------
// Prep: unchanged (validated arithmetic; R3 fragment layout; eslots E).
// ---------------------------------------------------------------------------
__global__ __launch_bounds__(256) void vq_prep(const float* __restrict__ cb,
                                               float* __restrict__ hcsq,
                                               char* __restrict__ stream,
                                               float* __restrict__ eslots) {
    const int k = blockIdx.x * 256 + threadIdx.x;   // 0..1023
    const float4* row = (const float4*)(cb + (size_t)k * DIM);
    char* base = stream + (size_t)(k >> 4) * TILEB + (size_t)(k & 15) * 16;
    float s = 0.f, r2 = 0.f;
#pragma unroll
    for (int i = 0; i < 8; ++i) {   // chunk i: halves i*8..i*8+7
        float4 a = row[2 * i], b = row[2 * i + 1];
        float v[8] = {a.x, a.y, a.z, a.w, b.x, b.y, b.z, b.w};
        union { half8 f; _Float16 e[8]; } uh;
#pragma unroll
        for (int j = 0; j < 8; ++j) {
            float c = v[j];
            s += c * c;                    // sequential chain (matches r4/r1)
            _Float16 h = (_Float16)c;      // RNE
            uh.e[j] = h;
            float d = c - (float)h;        // true residual
            r2 += d * d;
        }
        // chunk i -> j = i>>2 slot, q-position = i&3 (validated R3 layout)
        *(half8*)(base + ((i >> 2) << 10) + ((i & 3) << 8)) = uh.f;
    }
    hcsq[k] = 0.5f * s;
    float w = r2;
#pragma unroll
    for (int off = 1; off < 64; off <<= 1) w = fmaxf(w, __shfl_xor(w, off));
    if ((threadIdx.x & 63) == 0)
        eslots[blockIdx.x * 4 + (threadIdx.x >> 6)] = w;   // plain store
}

// ---------------------------------------------------------------------------
// Main. R3's 97-us loop body VERBATIM + R9's block-pooled rescue, with the
// R9 tail fix: the rescue was 21 us/row (vs 2 us standalone) because the
// 64-VGPR allocation serialized the unroll-8 load pipeline -- a wave's
// serial exposed-latency chain is NOT shortened by TLP. R10: launch_bounds
// (256,2) lifts the VGPR cap (main loop proven insensitive to 4-vs-8
// waves/SIMD in R2), and the rescue inner loop is manually staged 8-wide
// (8 named loads -> 8 dots -> 8 shuffle chains -> serial compare in
// ascending code order, preserving the validated min-index tie-break).
// Rescue also reads nshc from LDS (still live; s = p + nshc[c]).
// ---------------------------------------------------------------------------
#define SELECT(aa, ab, tl)                                                        \
    {                                                                             \
        const int _tl = (tl);                                                     \
        _Pragma("unroll")                                                         \
        for (int r = 0; r < 4; ++r) {                                             \
            float s0 = (aa)[r];                                                   \
            bool g0 = s0 > best[0][r];                                            \
            second[0][r] = __builtin_amdgcn_fmed3f(s0, best[0][r], second[0][r]); \
            best[0][r] = g0 ? s0 : best[0][r];                                    \
            btile[0][r] = g0 ? _tl : btile[0][r];                                 \
            float s1 = (ab)[r];                                                   \
            bool g1 = s1 > best[1][r];                                            \
            second[1][r] = __builtin_amdgcn_fmed3f(s1, best[1][r], second[1][r]); \
            best[1][r] = g1 ? s1 : best[1][r];                                    \
            btile[1][r] = g1 ? _tl : btile[1][r];                                 \
        }                                                                         \
    }

#define PHASE(fA, fB, a0, a1, o0, o1, TT)                     \
    {                                                         \
        const int _T = (TT);                                  \
        float nh = nshc[_T * 16 + m];                         \
        SELECT(o0, o1, _T - 1);                               \
        a0 = (f32x4){nh, nh, nh, nh};                         \
        a1 = a0;                                              \
        MFMA16(a0, xh[0][0], fA); MFMA16(a1, xh[1][0], fA);   \
        MFMA16(a0, xh[0][1], fB); MFMA16(a1, xh[1][1], fB);   \
        MFMA16(a0, xl[0][0], fA); MFMA16(a1, xl[1][0], fA);   \
        MFMA16(a0, xl[0][1], fB); MFMA16(a1, xl[1][1], fB);   \
        fA = *(const half8*)(gpre);                           \
        fB = *(const half8*)(gpre + 1024);                    \
        gpre += TILEB;                                        \
    }

// One staged rescue candidate group: load+dot (J = 0..7 -> code cbase+4J).
#define RESC_CHAIN(pv)                       \
    pv += __shfl_xor(pv, 1);                 \
    pv += __shfl_xor(pv, 2);                 \
    pv += __shfl_xor(pv, 4);                 \
    pv += __shfl_xor(pv, 8);

__global__ __launch_bounds__(256, 2) void vq_main(const float* __restrict__ inputs,
                                                  const float* __restrict__ cb,
                                                  const float* __restrict__ hcsq,
                                                  const char* __restrict__ stream,
                                                  const float* __restrict__ eslots,
                                                  float* __restrict__ out) {
    __shared__ float nshc[NCODES];     // negated 0.5||c||^2 (4 KB, loaded once)
    __shared__ unsigned s_rows[128];   // block-pooled flagged rows
    __shared__ unsigned s_cnt;
    const int tid = threadIdx.x;
    const int lane = tid & 63;
    const int wave = tid >> 6;
    const int m = lane & 15;   // A row-in-tile / B code-in-tile / D col
    const int q = lane >> 4;   // k-quad
    const size_t rowbase = (size_t)blockIdx.x * 128 + (size_t)wave * 32;

    for (int i = tid; i < NCODES; i += 256) nshc[i] = -hcsq[i];
    if (tid == 0) s_cnt = 0u;

    float e2 = 0.f;
#pragma unroll
    for (int i = 0; i < 16; ++i) e2 = fmaxf(e2, eslots[i]);
    const float E = sqrtf(e2) * 1.001f;

    // A fragments (fp16 hi+lo of x) + exact row sum-of-squares for the margin.
    half8 xh[2][2], xl[2][2];
    float xsq[2];
#pragma unroll
    for (int t = 0; t < 2; ++t) {
        const float* px = inputs + (rowbase + t * 16 + m) * DIM;
        float acc = 0.f;
#pragma unroll
        for (int s = 0; s < 2; ++s) {
            const float4* p = (const float4*)(px + q * 8 + s * 32);
            float4 v0 = p[0], v1 = p[1];
            float v[8] = {v0.x, v0.y, v0.z, v0.w, v1.x, v1.y, v1.z, v1.w};
            union { half8 f; _Float16 e[8]; } uh, ul;
#pragma unroll
            for (int j = 0; j < 8; ++j) {
                acc += v[j] * v[j];
                _Float16 h = (_Float16)v[j];
                uh.e[j] = h;
                ul.e[j] = (_Float16)(v[j] - (float)h);
            }
            xh[t][s] = uh.f;
            xl[t][s] = ul.f;
        }
        acc += __shfl_xor(acc, 16);   // reduce across k-quads (same m)
        acc += __shfl_xor(acc, 32);
        xsq[t] = acc;
    }
    __syncthreads();   // nshc + s_cnt ready

    float best[2][4], second[2][4];
    int btile[2][4];
#pragma unroll
    for (int t = 0; t < 2; ++t)
#pragma unroll
        for (int r = 0; r < 4; ++r) {
            best[t][r] = -INFINITY;
            second[t][r] = -INFINITY;
            btile[t][r] = 0;
        }

    // 4-tile rotating register prefetch pipeline (R3-verbatim).
    const char* gL = stream + (size_t)lane * 16;
    half8 f0a = *(const half8*)(gL);
    half8 f0b = *(const half8*)(gL + 1024);
    half8 f1a = *(const half8*)(gL + TILEB);
    half8 f1b = *(const half8*)(gL + TILEB + 1024);
    half8 f2a = *(const half8*)(gL + 2 * TILEB);
    half8 f2b = *(const half8*)(gL + 2 * TILEB + 1024);
    half8 f3a = *(const half8*)(gL + 3 * TILEB);
    half8 f3b = *(const half8*)(gL + 3 * TILEB + 1024);
    const char* gpre = gL + 4 * TILEB;

    f32x4 accA0, accA1, accB0, accB1;
    accB0 = (f32x4){-INFINITY, -INFINITY, -INFINITY, -INFINITY};
    accB1 = accB0;

    for (int it = 0; it < 16; ++it) {
        const int T = it * 4;
        PHASE(f0a, f0b, accA0, accA1, accB0, accB1, T + 0);
        PHASE(f1a, f1b, accB0, accB1, accA0, accA1, T + 1);
        PHASE(f2a, f2b, accA0, accA1, accB0, accB1, T + 2);
        PHASE(f3a, f3b, accB0, accB1, accA0, accA1, T + 3);
    }
    SELECT(accB0, accB1, NTILES - 1);   // drain last pending tile

    // Top-2 merge; write non-flagged rows; pool flagged rows in LDS.
#pragma unroll
    for (int t = 0; t < 2; ++t)
#pragma unroll
        for (int r = 0; r < 4; ++r) {
            float b = best[t][r], sc = second[t][r];
            int bi = btile[t][r] * 16 + m;   // reconstruct code index
#pragma unroll
            for (int off = 1; off < 16; off <<= 1) {
                float ob = __shfl_xor(b, off);
                float os = __shfl_xor(sc, off);
                int oi = __shfl_xor(bi, off);
                sc = fmaxf(fmaxf(sc, os), fminf(b, ob));
                if (ob > b || (ob == b && oi < bi)) { b = ob; bi = oi; }
            }
            size_t row = rowbase + t * 16 + q * 4 + r;
            float xs = __shfl(xsq[t], (lane & 48) | (q * 4 + r));
            float marg = 2.0f * (sqrtf(xs) * E + 1e-3f);
            bool flg = (b - sc) < marg;   // group-uniform
            if (!flg) {
                const float4* src = (const float4*)(cb + (size_t)bi * DIM);
                ((float4*)(out + row * DIM))[m] = src[m];
            } else if (m == 0) {
                unsigned p = atomicAdd(&s_cnt, 1u);   // LDS atomic
                s_rows[p] = (unsigned)row;            // p < 128 by construction
            }
        }

    __syncthreads();   // pool complete
    const unsigned n = s_cnt;

    // Block-pooled exact rescue, manually staged 8-wide for ILP. Scans codes
    // in ascending order per lane-group (c = c32*32 + 4j + g), identical
    // order and tie-break to the validated standalone rescue.
    const float4* cb4 = (const float4*)cb;
    for (unsigned e = wave; e < n; e += 4) {
        const size_t row = s_rows[e];
        const int sub = lane & 15;  // dim quad
        const int g = lane >> 4;    // code within 4-group
        float4 xv = ((const float4*)(inputs + row * DIM))[sub];
        float rb = -INFINITY;
        int rbi = 0;
        for (int c32 = 0; c32 < 32; ++c32) {
            const int cbase = c32 * 32 + g;
            // stage 1: 8 independent loads (in flight together)
            float4 v0 = cb4[(size_t)(cbase +  0) * 16 + sub];
            float4 v1 = cb4[(size_t)(cbase +  4) * 16 + sub];
            float4 v2 = cb4[(size_t)(cbase +  8) * 16 + sub];
            float4 v3 = cb4[(size_t)(cbase + 12) * 16 + sub];
            float4 v4 = cb4[(size_t)(cbase + 16) * 16 + sub];
            float4 v5 = cb4[(size_t)(cbase + 20) * 16 + sub];
            float4 v6 = cb4[(size_t)(cbase + 24) * 16 + sub];
            float4 v7 = cb4[(size_t)(cbase + 28) * 16 + sub];
            // stage 2: dots
            float p0 = xv.x * v0.x + xv.y * v0.y + xv.z * v0.z + xv.w * v0.w;
            float p1 = xv.x * v1.x + xv.y * v1.y + xv.z * v1.z + xv.w * v1.w;
            float p2 = xv.x * v2.x + xv.y * v2.y + xv.z * v2.z + xv.w * v2.w;
            float p3 = xv.x * v3.x + xv.y * v3.y + xv.z * v3.z + xv.w * v3.w;
            float p4 = xv.x * v4.x + xv.y * v4.y + xv.z * v4.z + xv.w * v4.w;
            float p5 = xv.x * v5.x + xv.y * v5.y + xv.z * v5.z + xv.w * v5.w;
            float p6 = xv.x * v6.x + xv.y * v6.y + xv.z * v6.z + xv.w * v6.w;
            float p7 = xv.x * v7.x + xv.y * v7.y + xv.z * v7.z + xv.w * v7.w;
            // stage 3: 8 independent 4-deep shuffle chains
            RESC_CHAIN(p0); RESC_CHAIN(p1); RESC_CHAIN(p2); RESC_CHAIN(p3);
            RESC_CHAIN(p4); RESC_CHAIN(p5); RESC_CHAIN(p6); RESC_CHAIN(p7);
            // stage 4: serial compare in ascending code order (tie-break!)
            float s0 = p0 + nshc[cbase +  0];
            if (s0 > rb) { rb = s0; rbi = cbase; }
            float s1 = p1 + nshc[cbase +  4];
            if (s1 > rb) { rb = s1; rbi = cbase + 4; }
            float s2 = p2 + nshc[cbase +  8];
            if (s2 > rb) { rb = s2; rbi = cbase + 8; }
            float s3 = p3 + nshc[cbase + 12];
            if (s3 > rb) { rb = s3; rbi = cbase + 12; }
            float s4 = p4 + nshc[cbase + 16];
            if (s4 > rb) { rb = s4; rbi = cbase + 16; }
            float s5 = p5 + nshc[cbase + 20];
            if (s5 > rb) { rb = s5; rbi = cbase + 20; }
            float s6 = p6 + nshc[cbase + 24];
            if (s6 > rb) { rb = s6; rbi = cbase + 24; }
            float s7 = p7 + nshc[cbase + 28];
            if (s7 > rb) { rb = s7; rbi = cbase + 28; }
        }
#pragma unroll
        for (int off = 16; off < 64; off <<= 1) {
            float ob = __shfl_xor(rb, off);
            int oi = __shfl_xor(rbi, off);
            if (ob > rb || (ob == rb && oi < rbi)) { rb = ob; rbi = oi; }
        }
        out[row * DIM + lane] = cb[(size_t)rbi * DIM + lane];
    }
}

extern "C" void kernel_launch(void* const* d_in, const int* in_sizes, int n_in,
                              void* d_out, int out_size, void* d_ws, size_t ws_size,
                              hipStream_t stream_) {
    const float* inputs = (const float*)d_in[0];    // [262144, 64] fp32
    const float* cb = (const float*)d_in[1];        // [1024, 64] fp32
    float* out = (float*)d_out;

    // ws: hcsq f32[1024] | tile stream [68 x 2048 B] | eslots f32[16]
    char* ws = (char*)d_ws;
    float* hcsq = (float*)ws;                                       //   4 KiB
    char* strm = ws + 4096;                                         // 136 KiB
    float* eslots = (float*)(ws + 4096 + (NTILES + PADT) * TILEB);

    vq_prep<<<4, 256, 0, stream_>>>(cb, hcsq, strm, eslots);
    vq_main<<<NROWS / 128, 256, 0, stream_>>>(inputs, cb, hcsq, strm, eslots, out);
}